// Round 19
// baseline (114.209 us; speedup 1.0000x reference)
//
#include <hip/hip_runtime.h>
#include <hip/hip_bf16.h>

#define H_DIM 768
#define NHEAD 12
#define HDIM  64
#define S_LEN 2048
#define B_SZ  2
#define M_TOT (B_SZ * S_LEN)   // 4096
#define NQKV  (3 * H_DIM)      // 2304
#define LN_EPS 1e-5f
#define SM_C   0.1803368801f   // 0.125 * log2(e)

typedef __attribute__((ext_vector_type(8)))  short bf16x8;
typedef __attribute__((ext_vector_type(4)))  float f32x4;
typedef __attribute__((ext_vector_type(16))) float f32x16;
typedef __attribute__((ext_vector_type(4)))  int   i32x4;

static __device__ inline ushort f2bf(float x) {
    __hip_bfloat16 h = __float2bfloat16(x);
    ushort u;
    __builtin_memcpy(&u, &h, 2);
    return u;
}
static __device__ inline float bf2f(ushort u) {
    unsigned int v = ((unsigned int)u) << 16;
    float f;
    __builtin_memcpy(&f, &v, 4);
    return f;
}
// hardware packed f32->bf16 convert (RTNE), 1 instruction for 2 values
static __device__ inline unsigned cvt_pk_bf16(float lo, float hi) {
    unsigned r;
    asm("v_cvt_pk_bf16_f32 %0, %1, %2" : "=v"(r) : "v"(lo), "v"(hi));
    return r;
}

#define GLDS16(g, l) __builtin_amdgcn_global_load_lds( \
    (const __attribute__((address_space(1))) void*)(g), \
    (__attribute__((address_space(3))) void*)(l), 16, 0, 0)

// ---------------- prep: convert_x + convert_w + concat_bias (fused) --------
__global__ __launch_bounds__(256)
void prep(const float* __restrict__ hs,
          const float* __restrict__ Wq, const float* __restrict__ Wk,
          const float* __restrict__ Wv, const float* __restrict__ Wo,
          const float* __restrict__ bq, const float* __restrict__ bk,
          const float* __restrict__ bv,
          ushort* __restrict__ Xbf, ushort* __restrict__ Wcat,
          ushort* __restrict__ Wot, float* __restrict__ bcat)
{
    __shared__ ushort T[64][65];
    const int bid = blockIdx.x;
    const int t   = threadIdx.x;

    if (bid < 3072) {                       // convert_x
        const int i = (bid * 256 + t) * 4;
        f32x4 v = *(const f32x4*)(hs + i);
        ushort4 o;
        o.x = f2bf(v[0]); o.y = f2bf(v[1]); o.z = f2bf(v[2]); o.w = f2bf(v[3]);
        *(ushort4*)(Xbf + i) = o;
    } else if (bid < 3072 + 576) {          // convert_w (transpose to [n][k])
        const int bid2 = bid - 3072;
        const int z = bid2 / 144;
        const int rem = bid2 % 144;
        const int n0 = (rem / 12) * 64;
        const int k0 = (rem % 12) * 64;
        const float* W = (z == 0) ? Wq : (z == 1) ? Wk : (z == 2) ? Wv : Wo;
        const int r = t >> 2, c0 = (t & 3) * 16;
        const float* src = W + (size_t)(k0 + r) * H_DIM + n0 + c0;
        #pragma unroll
        for (int j = 0; j < 16; j += 4) {
            f32x4 v = *(const f32x4*)(src + j);
            #pragma unroll
            for (int jj = 0; jj < 4; ++jj) T[r][c0 + j + jj] = f2bf(v[jj]);
        }
        __syncthreads();
        bf16x8 o0, o1;
        #pragma unroll
        for (int j = 0; j < 8; ++j) {
            o0[j] = (short)T[c0 + j][r];
            o1[j] = (short)T[c0 + 8 + j][r];
        }
        ushort* dst = (z < 3)
            ? Wcat + (size_t)(z * 768 + n0 + r) * H_DIM + k0 + c0
            : Wot  + (size_t)(n0 + r) * H_DIM + k0 + c0;
        *(bf16x8*)dst       = o0;
        *(bf16x8*)(dst + 8) = o1;
    } else {                                // concat_bias
        const int i = (bid - 3648) * 256 + t;
        if (i < NQKV) {
            float v = (i < 768) ? bq[i] : (i < 1536) ? bk[i - 768] : bv[i - 1536];
            bcat[i] = v;
        }
    }
}

// ---------------- MFMA GEMM (QKV): three BK=32 sub-steps per barrier -------
// out = A·Bt + bias; Q cols pre-scaled; V cols fused-transposed to Vt.
__global__ __launch_bounds__(256)
void gemm_mfma(const ushort* __restrict__ A, const ushort* __restrict__ Bt,
               const float* __restrict__ bias, void* __restrict__ outp,
               ushort* __restrict__ vtp, int M, int N, int K,
               int nscale, float sfac)
{
    __shared__ ushort As[3][128 * 32];   // 24 KB
    __shared__ ushort Bs[3][128 * 32];   // 24 KB
    const int bn = blockIdx.x * 128;
    const int bm = blockIdx.y * 128;
    const int t  = threadIdx.x;
    const int w  = t >> 6, l = t & 63;
    const int lg = l >> 4, lr = l & 15;
    const int wr = w >> 1, wc = w & 1;

    f32x4 acc[4][4];
    #pragma unroll
    for (int i = 0; i < 4; ++i)
        #pragma unroll
        for (int j = 0; j < 4; ++j) acc[i][j] = (f32x4){0.f, 0.f, 0.f, 0.f};

    for (int k0 = 0; k0 < K; k0 += 96) {
        #pragma unroll
        for (int h3 = 0; h3 < 3; ++h3) {
            #pragma unroll
            for (int it = 0; it < 2; ++it) {
                const int g = it * 256 + t;
                const int r = g >> 2, cb = (g & 3) * 8;
                GLDS16(A  + (size_t)(bm + r) * K + k0 + h3 * 32 + cb,
                       (char*)As[h3] + g * 16);
                GLDS16(Bt + (size_t)(bn + r) * K + k0 + h3 * 32 + cb,
                       (char*)Bs[h3] + g * 16);
            }
        }
        __syncthreads();
        #pragma unroll
        for (int h3 = 0; h3 < 3; ++h3) {
            bf16x8 af[4], bfr[4];
            #pragma unroll
            for (int m16 = 0; m16 < 4; ++m16)
                af[m16] = *(const bf16x8*)&As[h3][(wr * 64 + m16 * 16 + lr) * 32 + lg * 8];
            #pragma unroll
            for (int n16 = 0; n16 < 4; ++n16)
                bfr[n16] = *(const bf16x8*)&Bs[h3][(wc * 64 + n16 * 16 + lr) * 32 + lg * 8];
            #pragma unroll
            for (int m16 = 0; m16 < 4; ++m16)
                #pragma unroll
                for (int n16 = 0; n16 < 4; ++n16)
                    acc[m16][n16] = __builtin_amdgcn_mfma_f32_16x16x32_bf16(
                        af[m16], bfr[n16], acc[m16][n16], 0, 0, 0);
        }
        __syncthreads();
    }

    #pragma unroll
    for (int m16 = 0; m16 < 4; ++m16) {
        #pragma unroll
        for (int n16 = 0; n16 < 4; ++n16) {
            const int col = bn + wc * 64 + n16 * 16 + lr;
            const float bcol = bias[col];
            const int row0 = bm + wr * 64 + m16 * 16 + lg * 4;
            float vv[4];
            #pragma unroll
            for (int r = 0; r < 4; ++r) {
                float v = acc[m16][n16][r] + bcol;
                if (col < nscale) v *= sfac;
                vv[r] = v;
            }
            if (col >= 1536) {
                const int dfull = col - 1536;
                const int hh = dfull >> 6, dd = dfull & 63;
                const int bb = row0 >> 11, ss = row0 & 2047;
                ushort4 pk;
                pk.x = f2bf(vv[0]); pk.y = f2bf(vv[1]);
                pk.z = f2bf(vv[2]); pk.w = f2bf(vv[3]);
                *(ushort4*)(vtp + ((size_t)(bb * NHEAD + hh) * HDIM + dd) * S_LEN + ss) = pk;
            } else {
                #pragma unroll
                for (int r = 0; r < 4; ++r)
                    ((ushort*)outp)[(size_t)(row0 + r) * N + col] = f2bf(vv[r]);
            }
        }
    }
}

// ---------------- out-GEMM: 64x96 tiles, three BK=32 sub-steps per barrier -
// Hb2 (bf16) = Cbf·Wot^T + bo + hs
__global__ __launch_bounds__(256)
void gemm_out96(const ushort* __restrict__ A, const ushort* __restrict__ Bt,
                const float* __restrict__ bias, const float* __restrict__ resid,
                ushort* __restrict__ outp)
{
    __shared__ ushort As[3][64 * 32];    // 12 KB
    __shared__ ushort Bs[3][96 * 32];    // 18 KB
    const int bn = blockIdx.x * 96;
    const int bm = blockIdx.y * 64;
    const int t  = threadIdx.x;
    const int w  = t >> 6, l = t & 63;
    const int lg = l >> 4, lr = l & 15;
    const int wr = w >> 1, wc = w & 1;

    f32x4 acc[2][3];
    #pragma unroll
    for (int i = 0; i < 2; ++i)
        #pragma unroll
        for (int j = 0; j < 3; ++j) acc[i][j] = (f32x4){0.f, 0.f, 0.f, 0.f};

    for (int k0 = 0; k0 < H_DIM; k0 += 96) {
        #pragma unroll
        for (int h3 = 0; h3 < 3; ++h3) {
            {   // A: 64x32 = 256 chunks of 16B
                const int r = t >> 2, cb = (t & 3) * 8;
                GLDS16(A + (size_t)(bm + r) * H_DIM + k0 + h3 * 32 + cb,
                       (char*)As[h3] + t * 16);
            }
            {   // B: 96x32 = 384 chunks
                const int r = t >> 2, cb = (t & 3) * 8;
                GLDS16(Bt + (size_t)(bn + r) * H_DIM + k0 + h3 * 32 + cb,
                       (char*)Bs[h3] + t * 16);
                if (t < 128) {
                    const int g = 256 + t;
                    const int r2 = g >> 2, cb2 = (g & 3) * 8;
                    GLDS16(Bt + (size_t)(bn + r2) * H_DIM + k0 + h3 * 32 + cb2,
                           (char*)Bs[h3] + g * 16);
                }
            }
        }
        __syncthreads();
        #pragma unroll
        for (int h3 = 0; h3 < 3; ++h3) {
            bf16x8 af[2], bfr[3];
            #pragma unroll
            for (int m16 = 0; m16 < 2; ++m16)
                af[m16] = *(const bf16x8*)&As[h3][(wr * 32 + m16 * 16 + lr) * 32 + lg * 8];
            #pragma unroll
            for (int n16 = 0; n16 < 3; ++n16)
                bfr[n16] = *(const bf16x8*)&Bs[h3][(wc * 48 + n16 * 16 + lr) * 32 + lg * 8];
            #pragma unroll
            for (int m16 = 0; m16 < 2; ++m16)
                #pragma unroll
                for (int n16 = 0; n16 < 3; ++n16)
                    acc[m16][n16] = __builtin_amdgcn_mfma_f32_16x16x32_bf16(
                        af[m16], bfr[n16], acc[m16][n16], 0, 0, 0);
        }
        __syncthreads();
    }

    #pragma unroll
    for (int m16 = 0; m16 < 2; ++m16) {
        #pragma unroll
        for (int n16 = 0; n16 < 3; ++n16) {
            const int col = bn + wc * 48 + n16 * 16 + lr;
            const float bcol = bias[col];
            const int row0 = bm + wr * 32 + m16 * 16 + lg * 4;
            #pragma unroll
            for (int r = 0; r < 4; ++r) {
                float v = acc[m16][n16][r] + bcol
                        + resid[(size_t)(row0 + r) * H_DIM + col];
                outp[(size_t)(row0 + r) * H_DIM + col] = f2bf(v);
            }
        }
    }
}

// ---------------- MFMA flash attention: swapped-QK 32x32, sigma-staged K ---
// (R12 structure, unchanged) K 3-buf depth-2, V 2-buf depth-1, counted vmcnt
// across raw s_barrier; sigma row-permuted K staging -> PV B-frags single
// b128; cvt_pk P-packing; XCD-chunked grid; kmarg single copy.
#define KT     64
#define ATT_QT 128
#define KVHALF (S_LEN / 2)
#define NTILES (KVHALF / KT)   // 16

__global__ __launch_bounds__(256, 3)
void attn_mfma(const ushort* __restrict__ Qbf, const ushort* __restrict__ Kbf,
               const ushort* __restrict__ Vt, const float* __restrict__ mask,
               ushort* __restrict__ Pp, float* __restrict__ lp)
{
    const int flat = blockIdx.x;
    const int wk   = (flat & 7) * 96 + (flat >> 3);
    const int qt   = wk & 15;
    const int c_   = wk >> 4;            // 0..47 = bz*12 + h
    const int h    = c_ % 12;
    const int bz   = c_ / 12;
    const int b    = bz >> 1, half = bz & 1;

    const int t  = threadIdx.x;
    const int w  = t >> 6, l = t & 63;
    const int l31 = l & 31, hi = l >> 5;
    const int q0 = qt * ATT_QT;
    const int kb0 = half * KVHALF;

    __shared__ ushort Ks[3][KT][64];     // 24 KB, swizzled, sigma-row-permuted
    __shared__ ushort Vs[2][HDIM][64];   // 16 KB, swizzled ([d][kv])
    __shared__ float  kmarg[KVHALF];     //  4 KB: 0 valid / -1e30 masked

    {   // stage kv-mask args once
        const int i = t * 4;
        f32x4 v = *(const f32x4*)(mask + b * S_LEN + kb0 + i);
        f32x4 o;
        #pragma unroll
        for (int j = 0; j < 4; ++j)
            o[j] = (v[j] >= 0.f) ? 0.f : -1e30f;
        *(f32x4*)&kmarg[i] = o;
    }

    const bool qnL = (mask[b * S_LEN + q0 + w * 32 + l31] < 0.f);

    // Q B-fragments: qa[k] = Q[q=l31][d = 16k + 8hi + j] (pre-scaled by SM_C)
    bf16x8 qa[4];
    {
        const ushort* qsrc = Qbf + (size_t)(b * S_LEN + q0 + w * 32 + l31) * NQKV
                           + h * HDIM + 8 * hi;
        #pragma unroll
        for (int k = 0; k < 4; ++k)
            qa[k] = *(const bf16x8*)(qsrc + 16 * k);
    }

    // staging geometry (T2 swizzle: source column pre-swizzled, LDS linear)
    const int u    = l >> 3;                    // 0..7
    const int scol = ((l & 7) ^ u) * 8;
    // sigma: LDS rows {w*16+u, w*16+u+8} take K rows {srcK, srcK+4}
    const int srcK = w * 16 + u + ((u & 4) ? 4 : 0);
    const int srow = w * 16 + u;                // V rows unpermuted
    const ushort* kLane = Kbf + (size_t)(b * S_LEN + kb0 + srcK) * NQKV
                        + h * HDIM + scol;
    const ushort* vLane = Vt + ((size_t)(b * NHEAD + h) * HDIM + srow) * S_LEN
                        + kb0 + scol;
    char* ldsK = (char*)Ks + w * 2048 + l * 16;
    char* ldsV = (char*)Vs + w * 2048 + l * 16;

    __syncthreads();   // kmarg visible; vmem fully drained

    // prologue: K(0), V(0), K(1)  (queue order matters for vmcnt counts)
    GLDS16(kLane, ldsK);
    GLDS16(kLane + (size_t)4 * NQKV, ldsK + 1024);
    GLDS16(vLane, ldsV);
    GLDS16(vLane + (size_t)8 * S_LEN, ldsV + 1024);
    GLDS16(kLane + (size_t)KT * NQKV, ldsK + 8192);
    GLDS16(kLane + (size_t)(KT + 4) * NQKV, ldsK + 8192 + 1024);

    float l_part = 0.f;
    f32x16 accO[2];
    #pragma unroll
    for (int dt = 0; dt < 2; ++dt)
        #pragma unroll
        for (int i = 0; i < 16; ++i) accO[dt][i] = 0.f;

    const int swzl = (l31 & 7) << 4;

    for (int tt = 0; tt < NTILES; ++tt) {
        // counted wait: tile tt's K+V landed; K(tt+1) pair may stay in flight
        if (tt < NTILES - 1) {
            asm volatile("s_waitcnt vmcnt(2)" ::: "memory");
        } else {
            asm volatile("s_waitcnt vmcnt(0)" ::: "memory");
        }
        __builtin_amdgcn_s_barrier();

        // issue prefetch: V(tt+1) depth-1, K(tt+2) depth-2
        if (tt + 1 < NTILES) {
            const ushort* vsrc = vLane + (size_t)(tt + 1) * KT;
            char* lv = ldsV + ((tt + 1) & 1) * 8192;
            GLDS16(vsrc, lv);
            GLDS16(vsrc + (size_t)8 * S_LEN, lv + 1024);
            if (tt + 2 < NTILES) {
                const ushort* ksrc = kLane + (size_t)(tt + 2) * KT * NQKV;
                char* lk = ldsK + ((tt + 2) % 3) * 8192;
                GLDS16(ksrc, lk);
                GLDS16(ksrc + (size_t)4 * NQKV, lk + 1024);
            }
        }

        const char* Kc = (const char*)Ks + (tt % 3) * 8192;
        const char* Vc = (const char*)Vs + (tt & 1) * 8192;

        #pragma unroll
        for (int kvt = 0; kvt < 2; ++kvt) {
            // ---- S^T = K · Q^T (sigma-permuted LDS rows; scale in Q) ----
            f32x16 sc;
            __builtin_amdgcn_s_setprio(1);
            {
                const char* abase = Kc + (kvt * 32 + l31) * 128;
                bf16x8 a0 = *(const bf16x8*)(abase + ((16 * hi +  0) ^ swzl));
                bf16x8 a1 = *(const bf16x8*)(abase + ((16 * hi + 32) ^ swzl));
                bf16x8 a2 = *(const bf16x8*)(abase + ((16 * hi + 64) ^ swzl));
                bf16x8 a3 = *(const bf16x8*)(abase + ((16 * hi + 96) ^ swzl));
                f32x16 z;
                #pragma unroll
                for (int i = 0; i < 16; ++i) z[i] = 0.f;
                sc = __builtin_amdgcn_mfma_f32_32x32x16_bf16(a0, qa[0], z, 0, 0, 0);
                sc = __builtin_amdgcn_mfma_f32_32x32x16_bf16(a1, qa[1], sc, 0, 0, 0);
                sc = __builtin_amdgcn_mfma_f32_32x32x16_bf16(a2, qa[2], sc, 0, 0, 0);
                sc = __builtin_amdgcn_mfma_f32_32x32x16_bf16(a3, qa[3], sc, 0, 0, 0);
            }
            __builtin_amdgcn_s_setprio(0);

            // ---- lane-local softmax: reg q4*4+r <-> logical kv =
            //      16*(q4>>1) + 8*hi + 4*(q4&1) + r  (sigma mapping) ----
            float p[16];
            const float* km = &kmarg[tt * 64 + kvt * 32];
            #pragma unroll
            for (int q4 = 0; q4 < 4; ++q4) {
                const int kvb = 16 * (q4 >> 1) + 8 * hi + 4 * (q4 & 1);
                f32x4 kq = *(const f32x4*)(km + kvb);
                #pragma unroll
                for (int r = 0; r < 4; ++r) {
                    float arg = sc[q4 * 4 + r] + kq[r];
                    arg = qnL ? 0.f : arg;
                    const float pv = exp2f(arg);
                    p[q4 * 4 + r] = pv;
                    l_part += pv;
                }
            }

            // ---- PV: A-frag = p[0..7]/p[8..15] in order; B-frag = b128 ----
            __builtin_amdgcn_s_setprio(1);
            #pragma unroll
            for (int cc = 0; cc < 2; ++cc) {
                i32x4 pku;
                pku[0] = (int)cvt_pk_bf16(p[8 * cc + 0], p[8 * cc + 1]);
                pku[1] = (int)cvt_pk_bf16(p[8 * cc + 2], p[8 * cc + 3]);
                pku[2] = (int)cvt_pk_bf16(p[8 * cc + 4], p[8 * cc + 5]);
                pku[3] = (int)cvt_pk_bf16(p[8 * cc + 6], p[8 * cc + 7]);
                bf16x8 pa;
                __builtin_memcpy(&pa, &pku, 16);
                const int c = kvt * 2 + cc;   // kv chunk of 16 within tile
                #pragma unroll
                for (int dt = 0; dt < 2; ++dt) {
                    bf16x8 bv = *(const bf16x8*)(Vc + (32 * dt + l31) * 128
                                                 + ((32 * c + 16 * hi) ^ swzl));
                    accO[dt] = __builtin_amdgcn_mfma_f32_32x32x16_bf16(
                        pa, bv, accO[dt], 0, 0, 0);
                }
            }
            __builtin_amdgcn_s_setprio(0);
        }
    }

    // full denominator for q = l31: sum the two lane-halves
    l_part += __shfl_xor(l_part, 32, 64);

    // write unnormalized partial O (bf16) + l (f32)
    const size_t MN = (size_t)M_TOT * H_DIM;
    #pragma unroll
    for (int dt = 0; dt < 2; ++dt) {
        #pragma unroll
        for (int reg = 0; reg < 16; ++reg) {
            const int q = (reg & 3) + 8 * (reg >> 2) + 4 * hi;
            const int m = b * S_LEN + q0 + w * 32 + q;
            Pp[(size_t)half * MN + (size_t)m * H_DIM + h * HDIM + 32 * dt + l31]
                = f2bf(accO[dt][reg]);
        }
    }
    if (hi == 0) {
        const int m = b * S_LEN + q0 + w * 32 + l31;
        lp[half * (M_TOT * NHEAD) + m * NHEAD + h] = l_part;
    }
}

// ---------------- combine: ctx = (P0+P1)/(l0+l1) ---------------------------
__global__ __launch_bounds__(256)
void combine_kernel(const ushort* __restrict__ Pp, const float* __restrict__ lp,
                    ushort* __restrict__ ctx)
{
    const int idx = blockIdx.x * 256 + threadIdx.x;   // over M_TOT*96
    const int m  = idx / 96;
    const int c8 = idx % 96;
    const int c  = c8 * 8;
    const int h  = c8 >> 3;
    const size_t MN = (size_t)M_TOT * H_DIM;

    const float lsum = lp[m * NHEAD + h] + lp[M_TOT * NHEAD + m * NHEAD + h];
    const float inv  = 1.0f / lsum;

    bf16x8 a = *(const bf16x8*)(Pp + (size_t)m * H_DIM + c);
    bf16x8 b = *(const bf16x8*)(Pp + MN + (size_t)m * H_DIM + c);
    bf16x8 o;
    #pragma unroll
    for (int j = 0; j < 8; ++j)
        o[j] = (short)f2bf((bf2f((ushort)a[j]) + bf2f((ushort)b[j])) * inv);
    *(bf16x8*)(ctx + (size_t)m * H_DIM + c) = o;
}

// ---------------- LayerNorm (bf16 input, wave-per-row, shuffle reduce) -----
__global__ __launch_bounds__(256)
void ln_kernel(const ushort* __restrict__ Hbuf, const float* __restrict__ gamma,
               const float* __restrict__ beta, float* __restrict__ out)
{
    const int m = blockIdx.x * 4 + (threadIdx.x >> 6);
    const int l = threadIdx.x & 63;
    const ushort* row = Hbuf + (size_t)m * H_DIM;

    float x[12];
    #pragma unroll
    for (int k = 0; k < 3; ++k) {
        ushort4 v = *(const ushort4*)(row + l * 4 + k * 256);
        x[k * 4 + 0] = bf2f(v.x);
        x[k * 4 + 1] = bf2f(v.y);
        x[k * 4 + 2] = bf2f(v.z);
        x[k * 4 + 3] = bf2f(v.w);
    }

    float s = 0.f;
    #pragma unroll
    for (int j = 0; j < 12; ++j) s += x[j];
    #pragma unroll
    for (int off = 1; off < 64; off <<= 1) s += __shfl_xor(s, off, 64);
    const float mu = s * (1.0f / H_DIM);

    float v = 0.f;
    #pragma unroll
    for (int j = 0; j < 12; ++j) {
        const float d = x[j] - mu;
        v += d * d;
    }
    #pragma unroll
    for (int off = 1; off < 64; off <<= 1) v += __shfl_xor(v, off, 64);
    const float rstd = rsqrtf(v * (1.0f / H_DIM) + LN_EPS);

    #pragma unroll
    for (int k = 0; k < 3; ++k) {
        const int c = l * 4 + k * 256;
        f32x4 gm = *(const f32x4*)(gamma + c);
        f32x4 bt = *(const f32x4*)(beta + c);
        f32x4 o;
        #pragma unroll
        for (int j = 0; j < 4; ++j)
            o[j] = (x[k * 4 + j] - mu) * rstd * gm[j] + bt[j];
        *(f32x4*)(out + (size_t)m * H_DIM + c) = o;
    }
}

// ---------------------------------------------------------------------------
extern "C" void kernel_launch(void* const* d_in, const int* in_sizes, int n_in,
                              void* d_out, int out_size, void* d_ws, size_t ws_size,
                              hipStream_t stream)
{
    const float* hs   = (const float*)d_in[0];
    const float* mask = (const float*)d_in[1];
    const float* Wq   = (const float*)d_in[2];
    const float* bq   = (const float*)d_in[3];
    const float* Wk   = (const float*)d_in[4];
    const float* bk   = (const float*)d_in[5];
    const float* Wv   = (const float*)d_in[6];
    const float* bv   = (const float*)d_in[7];
    const float* Wo   = (const float*)d_in[8];
    const float* bo   = (const float*)d_in[9];
    const float* g    = (const float*)d_in[10];
    const float* be   = (const float*)d_in[11];
    float* out = (float*)d_out;

    char* base = (char*)d_ws;
    ushort* Xbf    = (ushort*)(base);                    //  6,291,456 B (Hb2 later)
    ushort* QKVbf  = (ushort*)(base + 6291456);          // 18,874,368 B
    ushort* Wcat   = (ushort*)(base + 25165824);         //  3,538,944 B (lp after QKV gemm)
    ushort* Wot    = (ushort*)(base + 28704768);         //  1,179,648 B
    float*  bcat   = (float*) (base + 29884416);         //      9,216 B
    ushort* Vt     = (ushort*)(base + 29893632);         //  6,291,456 B
    ushort* Cbf    = (ushort*)(base + 36185088);         //  6,291,456 B
    ushort* Pp     = (ushort*)(base + 42476544);         // 12,582,912 B
    float*  lp     = (float*) (base + 25165824);         // reuse Wcat region
    ushort* Hb2    = Xbf;                                // reuse Xbf region (bf16)

    prep<<<3657, 256, 0, stream>>>(hs, Wq, Wk, Wv, Wo, bq, bk, bv,
                                   Xbf, Wcat, Wot, bcat);

    // Q cols (<768) pre-scaled by SM_C; V cols (>=1536) fused-transposed to Vt
    gemm_mfma<<<dim3(NQKV / 128, M_TOT / 128), 256, 0, stream>>>(
        Xbf, Wcat, bcat, QKVbf, Vt, M_TOT, NQKV, H_DIM, 768, SM_C);

    attn_mfma<<<768, 256, 0, stream>>>(
        QKVbf, QKVbf + 768, Vt, mask, Pp, lp);

    combine_kernel<<<M_TOT * 96 / 256, 256, 0, stream>>>(Pp, lp, Cbf);

    gemm_out96<<<dim3(H_DIM / 96, M_TOT / 64), 256, 0, stream>>>(
        Cbf, Wot, bo, hs, Hb2);

    ln_kernel<<<M_TOT / 4, 256, 0, stream>>>(Hb2, g, be, out);
}

// Round 20
// 109.933 us; speedup vs baseline: 1.0389x; 1.0389x over previous
//
#include <hip/hip_runtime.h>
#include <hip/hip_bf16.h>

#define H_DIM 768
#define NHEAD 12
#define HDIM  64
#define S_LEN 2048
#define B_SZ  2
#define M_TOT (B_SZ * S_LEN)   // 4096
#define NQKV  (3 * H_DIM)      // 2304
#define LN_EPS 1e-5f
#define SM_C   0.1803368801f   // 0.125 * log2(e)

typedef __attribute__((ext_vector_type(8)))  short bf16x8;
typedef __attribute__((ext_vector_type(4)))  float f32x4;
typedef __attribute__((ext_vector_type(16))) float f32x16;
typedef __attribute__((ext_vector_type(4)))  int   i32x4;

static __device__ inline ushort f2bf(float x) {
    __hip_bfloat16 h = __float2bfloat16(x);
    ushort u;
    __builtin_memcpy(&u, &h, 2);
    return u;
}
static __device__ inline float bf2f(ushort u) {
    unsigned int v = ((unsigned int)u) << 16;
    float f;
    __builtin_memcpy(&f, &v, 4);
    return f;
}
// hardware packed f32->bf16 convert (RTNE), 1 instruction for 2 values
static __device__ inline unsigned cvt_pk_bf16(float lo, float hi) {
    unsigned r;
    asm("v_cvt_pk_bf16_f32 %0, %1, %2" : "=v"(r) : "v"(lo), "v"(hi));
    return r;
}

#define GLDS16(g, l) __builtin_amdgcn_global_load_lds( \
    (const __attribute__((address_space(1))) void*)(g), \
    (__attribute__((address_space(3))) void*)(l), 16, 0, 0)

// ---------------- prep: convert_x + convert_w + concat_bias (fused) --------
__global__ __launch_bounds__(256)
void prep(const float* __restrict__ hs,
          const float* __restrict__ Wq, const float* __restrict__ Wk,
          const float* __restrict__ Wv, const float* __restrict__ Wo,
          const float* __restrict__ bq, const float* __restrict__ bk,
          const float* __restrict__ bv,
          ushort* __restrict__ Xbf, ushort* __restrict__ Wcat,
          ushort* __restrict__ Wot, float* __restrict__ bcat)
{
    __shared__ ushort T[64][65];
    const int bid = blockIdx.x;
    const int t   = threadIdx.x;

    if (bid < 3072) {                       // convert_x
        const int i = (bid * 256 + t) * 4;
        f32x4 v = *(const f32x4*)(hs + i);
        ushort4 o;
        o.x = f2bf(v[0]); o.y = f2bf(v[1]); o.z = f2bf(v[2]); o.w = f2bf(v[3]);
        *(ushort4*)(Xbf + i) = o;
    } else if (bid < 3072 + 576) {          // convert_w (transpose to [n][k])
        const int bid2 = bid - 3072;
        const int z = bid2 / 144;
        const int rem = bid2 % 144;
        const int n0 = (rem / 12) * 64;
        const int k0 = (rem % 12) * 64;
        const float* W = (z == 0) ? Wq : (z == 1) ? Wk : (z == 2) ? Wv : Wo;
        const int r = t >> 2, c0 = (t & 3) * 16;
        const float* src = W + (size_t)(k0 + r) * H_DIM + n0 + c0;
        #pragma unroll
        for (int j = 0; j < 16; j += 4) {
            f32x4 v = *(const f32x4*)(src + j);
            #pragma unroll
            for (int jj = 0; jj < 4; ++jj) T[r][c0 + j + jj] = f2bf(v[jj]);
        }
        __syncthreads();
        bf16x8 o0, o1;
        #pragma unroll
        for (int j = 0; j < 8; ++j) {
            o0[j] = (short)T[c0 + j][r];
            o1[j] = (short)T[c0 + 8 + j][r];
        }
        ushort* dst = (z < 3)
            ? Wcat + (size_t)(z * 768 + n0 + r) * H_DIM + k0 + c0
            : Wot  + (size_t)(n0 + r) * H_DIM + k0 + c0;
        *(bf16x8*)dst       = o0;
        *(bf16x8*)(dst + 8) = o1;
    } else {                                // concat_bias
        const int i = (bid - 3648) * 256 + t;
        if (i < NQKV) {
            float v = (i < 768) ? bq[i] : (i < 1536) ? bk[i - 768] : bv[i - 1536];
            bcat[i] = v;
        }
    }
}

// ---------------- MFMA GEMM (QKV): two BK=32 sub-steps per barrier period --
// out = A·Bt + bias; Q cols pre-scaled; V cols fused-transposed to Vt.
__global__ __launch_bounds__(256)
void gemm_mfma(const ushort* __restrict__ A, const ushort* __restrict__ Bt,
               const float* __restrict__ bias, void* __restrict__ outp,
               ushort* __restrict__ vtp, int M, int N, int K,
               int nscale, float sfac)
{
    __shared__ ushort As[2][128 * 32];   // 16 KB
    __shared__ ushort Bs[2][128 * 32];   // 16 KB
    const int bn = blockIdx.x * 128;
    const int bm = blockIdx.y * 128;
    const int t  = threadIdx.x;
    const int w  = t >> 6, l = t & 63;
    const int lg = l >> 4, lr = l & 15;
    const int wr = w >> 1, wc = w & 1;

    f32x4 acc[4][4];
    #pragma unroll
    for (int i = 0; i < 4; ++i)
        #pragma unroll
        for (int j = 0; j < 4; ++j) acc[i][j] = (f32x4){0.f, 0.f, 0.f, 0.f};

    for (int k0 = 0; k0 < K; k0 += 64) {
        #pragma unroll
        for (int h2 = 0; h2 < 2; ++h2) {
            #pragma unroll
            for (int it = 0; it < 2; ++it) {
                const int g = it * 256 + t;
                const int r = g >> 2, cb = (g & 3) * 8;
                GLDS16(A  + (size_t)(bm + r) * K + k0 + h2 * 32 + cb,
                       (char*)As[h2] + g * 16);
                GLDS16(Bt + (size_t)(bn + r) * K + k0 + h2 * 32 + cb,
                       (char*)Bs[h2] + g * 16);
            }
        }
        __syncthreads();
        #pragma unroll
        for (int h2 = 0; h2 < 2; ++h2) {
            bf16x8 af[4], bfr[4];
            #pragma unroll
            for (int m16 = 0; m16 < 4; ++m16)
                af[m16] = *(const bf16x8*)&As[h2][(wr * 64 + m16 * 16 + lr) * 32 + lg * 8];
            #pragma unroll
            for (int n16 = 0; n16 < 4; ++n16)
                bfr[n16] = *(const bf16x8*)&Bs[h2][(wc * 64 + n16 * 16 + lr) * 32 + lg * 8];
            #pragma unroll
            for (int m16 = 0; m16 < 4; ++m16)
                #pragma unroll
                for (int n16 = 0; n16 < 4; ++n16)
                    acc[m16][n16] = __builtin_amdgcn_mfma_f32_16x16x32_bf16(
                        af[m16], bfr[n16], acc[m16][n16], 0, 0, 0);
        }
        __syncthreads();
    }

    #pragma unroll
    for (int m16 = 0; m16 < 4; ++m16) {
        #pragma unroll
        for (int n16 = 0; n16 < 4; ++n16) {
            const int col = bn + wc * 64 + n16 * 16 + lr;
            const float bcol = bias[col];
            const int row0 = bm + wr * 64 + m16 * 16 + lg * 4;
            float vv[4];
            #pragma unroll
            for (int r = 0; r < 4; ++r) {
                float v = acc[m16][n16][r] + bcol;
                if (col < nscale) v *= sfac;
                vv[r] = v;
            }
            if (col >= 1536) {
                const int dfull = col - 1536;
                const int hh = dfull >> 6, dd = dfull & 63;
                const int bb = row0 >> 11, ss = row0 & 2047;
                ushort4 pk;
                pk.x = f2bf(vv[0]); pk.y = f2bf(vv[1]);
                pk.z = f2bf(vv[2]); pk.w = f2bf(vv[3]);
                *(ushort4*)(vtp + ((size_t)(bb * NHEAD + hh) * HDIM + dd) * S_LEN + ss) = pk;
            } else {
                #pragma unroll
                for (int r = 0; r < 4; ++r)
                    ((ushort*)outp)[(size_t)(row0 + r) * N + col] = f2bf(vv[r]);
            }
        }
    }
}

// ---------------- out-GEMM: 64x96 tiles, two BK=32 sub-steps per barrier ---
// Hb2 (bf16) = Cbf·Wot^T + bo + hs
__global__ __launch_bounds__(256)
void gemm_out96(const ushort* __restrict__ A, const ushort* __restrict__ Bt,
                const float* __restrict__ bias, const float* __restrict__ resid,
                ushort* __restrict__ outp)
{
    __shared__ ushort As[2][64 * 32];    // 8 KB
    __shared__ ushort Bs[2][96 * 32];    // 12 KB
    const int bn = blockIdx.x * 96;
    const int bm = blockIdx.y * 64;
    const int t  = threadIdx.x;
    const int w  = t >> 6, l = t & 63;
    const int lg = l >> 4, lr = l & 15;
    const int wr = w >> 1, wc = w & 1;

    f32x4 acc[2][3];
    #pragma unroll
    for (int i = 0; i < 2; ++i)
        #pragma unroll
        for (int j = 0; j < 3; ++j) acc[i][j] = (f32x4){0.f, 0.f, 0.f, 0.f};

    for (int k0 = 0; k0 < H_DIM; k0 += 64) {
        #pragma unroll
        for (int h2 = 0; h2 < 2; ++h2) {
            {   // A: 64x32 = 256 chunks of 16B
                const int r = t >> 2, cb = (t & 3) * 8;
                GLDS16(A + (size_t)(bm + r) * H_DIM + k0 + h2 * 32 + cb,
                       (char*)As[h2] + t * 16);
            }
            {   // B: 96x32 = 384 chunks
                const int r = t >> 2, cb = (t & 3) * 8;
                GLDS16(Bt + (size_t)(bn + r) * H_DIM + k0 + h2 * 32 + cb,
                       (char*)Bs[h2] + t * 16);
                if (t < 128) {
                    const int g = 256 + t;
                    const int r2 = g >> 2, cb2 = (g & 3) * 8;
                    GLDS16(Bt + (size_t)(bn + r2) * H_DIM + k0 + h2 * 32 + cb2,
                           (char*)Bs[h2] + g * 16);
                }
            }
        }
        __syncthreads();
        #pragma unroll
        for (int h2 = 0; h2 < 2; ++h2) {
            bf16x8 af[2], bfr[3];
            #pragma unroll
            for (int m16 = 0; m16 < 2; ++m16)
                af[m16] = *(const bf16x8*)&As[h2][(wr * 32 + m16 * 16 + lr) * 32 + lg * 8];
            #pragma unroll
            for (int n16 = 0; n16 < 3; ++n16)
                bfr[n16] = *(const bf16x8*)&Bs[h2][(wc * 48 + n16 * 16 + lr) * 32 + lg * 8];
            #pragma unroll
            for (int m16 = 0; m16 < 2; ++m16)
                #pragma unroll
                for (int n16 = 0; n16 < 3; ++n16)
                    acc[m16][n16] = __builtin_amdgcn_mfma_f32_16x16x32_bf16(
                        af[m16], bfr[n16], acc[m16][n16], 0, 0, 0);
        }
        __syncthreads();
    }

    #pragma unroll
    for (int m16 = 0; m16 < 2; ++m16) {
        #pragma unroll
        for (int n16 = 0; n16 < 3; ++n16) {
            const int col = bn + wc * 48 + n16 * 16 + lr;
            const float bcol = bias[col];
            const int row0 = bm + wr * 32 + m16 * 16 + lg * 4;
            #pragma unroll
            for (int r = 0; r < 4; ++r) {
                float v = acc[m16][n16][r] + bcol
                        + resid[(size_t)(row0 + r) * H_DIM + col];
                outp[(size_t)(row0 + r) * H_DIM + col] = f2bf(v);
            }
        }
    }
}

// ---------------- MFMA flash attention: swapped-QK 32x32, sigma-staged K ---
// (R12 structure, unchanged) K 3-buf depth-2, V 2-buf depth-1, counted vmcnt
// across raw s_barrier; sigma row-permuted K staging -> PV B-frags single
// b128; cvt_pk P-packing; XCD-chunked grid; kmarg single copy.
#define KT     64
#define ATT_QT 128
#define KVHALF (S_LEN / 2)
#define NTILES (KVHALF / KT)   // 16

__global__ __launch_bounds__(256, 3)
void attn_mfma(const ushort* __restrict__ Qbf, const ushort* __restrict__ Kbf,
               const ushort* __restrict__ Vt, const float* __restrict__ mask,
               ushort* __restrict__ Pp, float* __restrict__ lp)
{
    const int flat = blockIdx.x;
    const int wk   = (flat & 7) * 96 + (flat >> 3);
    const int qt   = wk & 15;
    const int c_   = wk >> 4;            // 0..47 = bz*12 + h
    const int h    = c_ % 12;
    const int bz   = c_ / 12;
    const int b    = bz >> 1, half = bz & 1;

    const int t  = threadIdx.x;
    const int w  = t >> 6, l = t & 63;
    const int l31 = l & 31, hi = l >> 5;
    const int q0 = qt * ATT_QT;
    const int kb0 = half * KVHALF;

    __shared__ ushort Ks[3][KT][64];     // 24 KB, swizzled, sigma-row-permuted
    __shared__ ushort Vs[2][HDIM][64];   // 16 KB, swizzled ([d][kv])
    __shared__ float  kmarg[KVHALF];     //  4 KB: 0 valid / -1e30 masked

    {   // stage kv-mask args once
        const int i = t * 4;
        f32x4 v = *(const f32x4*)(mask + b * S_LEN + kb0 + i);
        f32x4 o;
        #pragma unroll
        for (int j = 0; j < 4; ++j)
            o[j] = (v[j] >= 0.f) ? 0.f : -1e30f;
        *(f32x4*)&kmarg[i] = o;
    }

    const bool qnL = (mask[b * S_LEN + q0 + w * 32 + l31] < 0.f);

    // Q B-fragments: qa[k] = Q[q=l31][d = 16k + 8hi + j] (pre-scaled by SM_C)
    bf16x8 qa[4];
    {
        const ushort* qsrc = Qbf + (size_t)(b * S_LEN + q0 + w * 32 + l31) * NQKV
                           + h * HDIM + 8 * hi;
        #pragma unroll
        for (int k = 0; k < 4; ++k)
            qa[k] = *(const bf16x8*)(qsrc + 16 * k);
    }

    // staging geometry (T2 swizzle: source column pre-swizzled, LDS linear)
    const int u    = l >> 3;                    // 0..7
    const int scol = ((l & 7) ^ u) * 8;
    // sigma: LDS rows {w*16+u, w*16+u+8} take K rows {srcK, srcK+4}
    const int srcK = w * 16 + u + ((u & 4) ? 4 : 0);
    const int srow = w * 16 + u;                // V rows unpermuted
    const ushort* kLane = Kbf + (size_t)(b * S_LEN + kb0 + srcK) * NQKV
                        + h * HDIM + scol;
    const ushort* vLane = Vt + ((size_t)(b * NHEAD + h) * HDIM + srow) * S_LEN
                        + kb0 + scol;
    char* ldsK = (char*)Ks + w * 2048 + l * 16;
    char* ldsV = (char*)Vs + w * 2048 + l * 16;

    __syncthreads();   // kmarg visible; vmem fully drained

    // prologue: K(0), V(0), K(1)  (queue order matters for vmcnt counts)
    GLDS16(kLane, ldsK);
    GLDS16(kLane + (size_t)4 * NQKV, ldsK + 1024);
    GLDS16(vLane, ldsV);
    GLDS16(vLane + (size_t)8 * S_LEN, ldsV + 1024);
    GLDS16(kLane + (size_t)KT * NQKV, ldsK + 8192);
    GLDS16(kLane + (size_t)(KT + 4) * NQKV, ldsK + 8192 + 1024);

    float l_part = 0.f;
    f32x16 accO[2];
    #pragma unroll
    for (int dt = 0; dt < 2; ++dt)
        #pragma unroll
        for (int i = 0; i < 16; ++i) accO[dt][i] = 0.f;

    const int swzl = (l31 & 7) << 4;

    for (int tt = 0; tt < NTILES; ++tt) {
        // counted wait: tile tt's K+V landed; K(tt+1) pair may stay in flight
        if (tt < NTILES - 1) {
            asm volatile("s_waitcnt vmcnt(2)" ::: "memory");
        } else {
            asm volatile("s_waitcnt vmcnt(0)" ::: "memory");
        }
        __builtin_amdgcn_s_barrier();

        // issue prefetch: V(tt+1) depth-1, K(tt+2) depth-2
        if (tt + 1 < NTILES) {
            const ushort* vsrc = vLane + (size_t)(tt + 1) * KT;
            char* lv = ldsV + ((tt + 1) & 1) * 8192;
            GLDS16(vsrc, lv);
            GLDS16(vsrc + (size_t)8 * S_LEN, lv + 1024);
            if (tt + 2 < NTILES) {
                const ushort* ksrc = kLane + (size_t)(tt + 2) * KT * NQKV;
                char* lk = ldsK + ((tt + 2) % 3) * 8192;
                GLDS16(ksrc, lk);
                GLDS16(ksrc + (size_t)4 * NQKV, lk + 1024);
            }
        }

        const char* Kc = (const char*)Ks + (tt % 3) * 8192;
        const char* Vc = (const char*)Vs + (tt & 1) * 8192;

        #pragma unroll
        for (int kvt = 0; kvt < 2; ++kvt) {
            // ---- S^T = K · Q^T (sigma-permuted LDS rows; scale in Q) ----
            f32x16 sc;
            __builtin_amdgcn_s_setprio(1);
            {
                const char* abase = Kc + (kvt * 32 + l31) * 128;
                bf16x8 a0 = *(const bf16x8*)(abase + ((16 * hi +  0) ^ swzl));
                bf16x8 a1 = *(const bf16x8*)(abase + ((16 * hi + 32) ^ swzl));
                bf16x8 a2 = *(const bf16x8*)(abase + ((16 * hi + 64) ^ swzl));
                bf16x8 a3 = *(const bf16x8*)(abase + ((16 * hi + 96) ^ swzl));
                f32x16 z;
                #pragma unroll
                for (int i = 0; i < 16; ++i) z[i] = 0.f;
                sc = __builtin_amdgcn_mfma_f32_32x32x16_bf16(a0, qa[0], z, 0, 0, 0);
                sc = __builtin_amdgcn_mfma_f32_32x32x16_bf16(a1, qa[1], sc, 0, 0, 0);
                sc = __builtin_amdgcn_mfma_f32_32x32x16_bf16(a2, qa[2], sc, 0, 0, 0);
                sc = __builtin_amdgcn_mfma_f32_32x32x16_bf16(a3, qa[3], sc, 0, 0, 0);
            }
            __builtin_amdgcn_s_setprio(0);

            // ---- lane-local softmax: reg q4*4+r <-> logical kv =
            //      16*(q4>>1) + 8*hi + 4*(q4&1) + r  (sigma mapping) ----
            float p[16];
            const float* km = &kmarg[tt * 64 + kvt * 32];
            #pragma unroll
            for (int q4 = 0; q4 < 4; ++q4) {
                const int kvb = 16 * (q4 >> 1) + 8 * hi + 4 * (q4 & 1);
                f32x4 kq = *(const f32x4*)(km + kvb);
                #pragma unroll
                for (int r = 0; r < 4; ++r) {
                    float arg = sc[q4 * 4 + r] + kq[r];
                    arg = qnL ? 0.f : arg;
                    const float pv = exp2f(arg);
                    p[q4 * 4 + r] = pv;
                    l_part += pv;
                }
            }

            // ---- PV: A-frag = p[0..7]/p[8..15] in order; B-frag = b128 ----
            __builtin_amdgcn_s_setprio(1);
            #pragma unroll
            for (int cc = 0; cc < 2; ++cc) {
                i32x4 pku;
                pku[0] = (int)cvt_pk_bf16(p[8 * cc + 0], p[8 * cc + 1]);
                pku[1] = (int)cvt_pk_bf16(p[8 * cc + 2], p[8 * cc + 3]);
                pku[2] = (int)cvt_pk_bf16(p[8 * cc + 4], p[8 * cc + 5]);
                pku[3] = (int)cvt_pk_bf16(p[8 * cc + 6], p[8 * cc + 7]);
                bf16x8 pa;
                __builtin_memcpy(&pa, &pku, 16);
                const int c = kvt * 2 + cc;   // kv chunk of 16 within tile
                #pragma unroll
                for (int dt = 0; dt < 2; ++dt) {
                    bf16x8 bv = *(const bf16x8*)(Vc + (32 * dt + l31) * 128
                                                 + ((32 * c + 16 * hi) ^ swzl));
                    accO[dt] = __builtin_amdgcn_mfma_f32_32x32x16_bf16(
                        pa, bv, accO[dt], 0, 0, 0);
                }
            }
            __builtin_amdgcn_s_setprio(0);
        }
    }

    // full denominator for q = l31: sum the two lane-halves
    l_part += __shfl_xor(l_part, 32, 64);

    // write unnormalized partial O (bf16) + l (f32)
    const size_t MN = (size_t)M_TOT * H_DIM;
    #pragma unroll
    for (int dt = 0; dt < 2; ++dt) {
        #pragma unroll
        for (int reg = 0; reg < 16; ++reg) {
            const int q = (reg & 3) + 8 * (reg >> 2) + 4 * hi;
            const int m = b * S_LEN + q0 + w * 32 + q;
            Pp[(size_t)half * MN + (size_t)m * H_DIM + h * HDIM + 32 * dt + l31]
                = f2bf(accO[dt][reg]);
        }
    }
    if (hi == 0) {
        const int m = b * S_LEN + q0 + w * 32 + l31;
        lp[half * (M_TOT * NHEAD) + m * NHEAD + h] = l_part;
    }
}

// ---------------- combine: ctx = (P0+P1)/(l0+l1) ---------------------------
__global__ __launch_bounds__(256)
void combine_kernel(const ushort* __restrict__ Pp, const float* __restrict__ lp,
                    ushort* __restrict__ ctx)
{
    const int idx = blockIdx.x * 256 + threadIdx.x;   // over M_TOT*96
    const int m  = idx / 96;
    const int c8 = idx % 96;
    const int c  = c8 * 8;
    const int h  = c8 >> 3;
    const size_t MN = (size_t)M_TOT * H_DIM;

    const float lsum = lp[m * NHEAD + h] + lp[M_TOT * NHEAD + m * NHEAD + h];
    const float inv  = 1.0f / lsum;

    bf16x8 a = *(const bf16x8*)(Pp + (size_t)m * H_DIM + c);
    bf16x8 b = *(const bf16x8*)(Pp + MN + (size_t)m * H_DIM + c);
    bf16x8 o;
    #pragma unroll
    for (int j = 0; j < 8; ++j)
        o[j] = (short)f2bf((bf2f((ushort)a[j]) + bf2f((ushort)b[j])) * inv);
    *(bf16x8*)(ctx + (size_t)m * H_DIM + c) = o;
}

// ---------------- LayerNorm (bf16 input, wave-per-row, shuffle reduce) -----
__global__ __launch_bounds__(256)
void ln_kernel(const ushort* __restrict__ Hbuf, const float* __restrict__ gamma,
               const float* __restrict__ beta, float* __restrict__ out)
{
    const int m = blockIdx.x * 4 + (threadIdx.x >> 6);
    const int l = threadIdx.x & 63;
    const ushort* row = Hbuf + (size_t)m * H_DIM;

    float x[12];
    #pragma unroll
    for (int k = 0; k < 3; ++k) {
        ushort4 v = *(const ushort4*)(row + l * 4 + k * 256);
        x[k * 4 + 0] = bf2f(v.x);
        x[k * 4 + 1] = bf2f(v.y);
        x[k * 4 + 2] = bf2f(v.z);
        x[k * 4 + 3] = bf2f(v.w);
    }

    float s = 0.f;
    #pragma unroll
    for (int j = 0; j < 12; ++j) s += x[j];
    #pragma unroll
    for (int off = 1; off < 64; off <<= 1) s += __shfl_xor(s, off, 64);
    const float mu = s * (1.0f / H_DIM);

    float v = 0.f;
    #pragma unroll
    for (int j = 0; j < 12; ++j) {
        const float d = x[j] - mu;
        v += d * d;
    }
    #pragma unroll
    for (int off = 1; off < 64; off <<= 1) v += __shfl_xor(v, off, 64);
    const float rstd = rsqrtf(v * (1.0f / H_DIM) + LN_EPS);

    #pragma unroll
    for (int k = 0; k < 3; ++k) {
        const int c = l * 4 + k * 256;
        f32x4 gm = *(const f32x4*)(gamma + c);
        f32x4 bt = *(const f32x4*)(beta + c);
        f32x4 o;
        #pragma unroll
        for (int j = 0; j < 4; ++j)
            o[j] = (x[k * 4 + j] - mu) * rstd * gm[j] + bt[j];
        *(f32x4*)(out + (size_t)m * H_DIM + c) = o;
    }
}

// ---------------------------------------------------------------------------
extern "C" void kernel_launch(void* const* d_in, const int* in_sizes, int n_in,
                              void* d_out, int out_size, void* d_ws, size_t ws_size,
                              hipStream_t stream)
{
    const float* hs   = (const float*)d_in[0];
    const float* mask = (const float*)d_in[1];
    const float* Wq   = (const float*)d_in[2];
    const float* bq   = (const float*)d_in[3];
    const float* Wk   = (const float*)d_in[4];
    const float* bk   = (const float*)d_in[5];
    const float* Wv   = (const float*)d_in[6];
    const float* bv   = (const float*)d_in[7];
    const float* Wo   = (const float*)d_in[8];
    const float* bo   = (const float*)d_in[9];
    const float* g    = (const float*)d_in[10];
    const float* be   = (const float*)d_in[11];
    float* out = (float*)d_out;

    char* base = (char*)d_ws;
    ushort* Xbf    = (ushort*)(base);                    //  6,291,456 B (Hb2 later)
    ushort* QKVbf  = (ushort*)(base + 6291456);          // 18,874,368 B
    ushort* Wcat   = (ushort*)(base + 25165824);         //  3,538,944 B (lp after QKV gemm)
    ushort* Wot    = (ushort*)(base + 28704768);         //  1,179,648 B
    float*  bcat   = (float*) (base + 29884416);         //      9,216 B
    ushort* Vt     = (ushort*)(base + 29893632);         //  6,291,456 B
    ushort* Cbf    = (ushort*)(base + 36185088);         //  6,291,456 B
    ushort* Pp     = (ushort*)(base + 42476544);         // 12,582,912 B
    float*  lp     = (float*) (base + 25165824);         // reuse Wcat region
    ushort* Hb2    = Xbf;                                // reuse Xbf region (bf16)

    prep<<<3657, 256, 0, stream>>>(hs, Wq, Wk, Wv, Wo, bq, bk, bv,
                                   Xbf, Wcat, Wot, bcat);

    // Q cols (<768) pre-scaled by SM_C; V cols (>=1536) fused-transposed to Vt
    gemm_mfma<<<dim3(NQKV / 128, M_TOT / 128), 256, 0, stream>>>(
        Xbf, Wcat, bcat, QKVbf, Vt, M_TOT, NQKV, H_DIM, 768, SM_C);

    attn_mfma<<<768, 256, 0, stream>>>(
        QKVbf, QKVbf + 768, Vt, mask, Pp, lp);

    combine_kernel<<<M_TOT * 96 / 256, 256, 0, stream>>>(Pp, lp, Cbf);

    gemm_out96<<<dim3(H_DIM / 96, M_TOT / 64), 256, 0, stream>>>(
        Cbf, Wot, bo, hs, Hb2);

    ln_kernel<<<M_TOT / 4, 256, 0, stream>>>(Hb2, g, be, out);
}